// Round 11
// baseline (148.176 us; speedup 1.0000x reference)
//
#include <hip/hip_runtime.h>

typedef __attribute__((ext_vector_type(4)))  float f32x4;
typedef __attribute__((ext_vector_type(16))) float f32x16;
typedef __attribute__((ext_vector_type(8)))  __bf16 bf16x8;
typedef __attribute__((ext_vector_type(8)))  unsigned short ushort8;

#define BATCH 8
#define CH    512
#define NN    1024   // H*W
#define GRP   32
#define NHEAD 8
#define DH    64
#define QBLK  128    // 4 waves x 32 q-rows per key-group (32x32 MFMA path)
#define KBLK  64

// ---- workspace layout (bytes) ----
static constexpr size_t OFF_STATS = 0;                                   // 512 f32
static constexpr size_t OFF_WQB   = 4096;                                // 1536*512 bf16
static constexpr size_t OFF_WPB   = OFF_WQB + (size_t)1536*512*2;
static constexpr size_t OFF_XNT   = OFF_WPB + (size_t)512*512*2;         // [b][n][c] bf16
static constexpr size_t OFF_QKB   = OFF_XNT + (size_t)BATCH*NN*CH*2;     // [b][n][1024] bf16 (Q|K), Q pre-scaled
static constexpr size_t OFF_VT    = OFF_QKB + (size_t)BATCH*NN*1024*2;   // [b][h][d][n] bf16
static constexpr size_t OFF_ATTNT = OFF_VT  + (size_t)BATCH*CH*NN*2;     // [b][n][c] bf16

static __device__ __forceinline__ unsigned short f2bf(float f){
  union { float f; unsigned u; } cv; cv.f = f;
  unsigned u = cv.u;
  u += 0x7fffu + ((u >> 16) & 1u);   // RNE
  return (unsigned short)(u >> 16);
}

static __device__ __forceinline__ unsigned pack2bf(float lo, float hi){
  union { __bf16 h[2]; unsigned u; } v;
  v.h[0] = (__bf16)lo; v.h[1] = (__bf16)hi;
  return v.u;
}

// v_permlane32_swap_b32: exchanges a's lanes 32..63 with b's lanes 0..31
static __device__ __forceinline__ void plswap(unsigned &a, unsigned &b){
  asm("v_permlane32_swap_b32 %0, %1" : "+v"(a), "+v"(b));
}

// async global->LDS, 16B per lane, dest = wave-uniform base + lane*16
static __device__ __forceinline__ void gload_lds16(const unsigned short* g, unsigned short* l){
  __builtin_amdgcn_global_load_lds((const __attribute__((address_space(1))) void*)g,
                                   (__attribute__((address_space(3))) void*)l, 16, 0, 0);
}

// ---- K1: fused (gn_stats | weight cvt) ----
__global__ __launch_bounds__(256) void pre_k(const float* __restrict__ x,
                                             const float* __restrict__ wq, const float* __restrict__ wp,
                                             float* __restrict__ stats,
                                             unsigned short* __restrict__ wqb, unsigned short* __restrict__ wpb){
  int bid = blockIdx.x;
  if (bid < 256){
    int bg = bid;
    const float4* base = (const float4*)(x + (size_t)bg * (16*NN));
    float s = 0.f, ss = 0.f;
    #pragma unroll 4
    for (int idx = threadIdx.x; idx < 16*NN/4; idx += 256){
      float4 v = base[idx];
      s  += (v.x + v.y) + (v.z + v.w);
      ss += (v.x*v.x + v.y*v.y) + (v.z*v.z + v.w*v.w);
    }
    for (int off = 32; off > 0; off >>= 1){ s += __shfl_down(s, off); ss += __shfl_down(ss, off); }
    __shared__ float red[8];
    int w = threadIdx.x >> 6, l = threadIdx.x & 63;
    if (l == 0){ red[w*2] = s; red[w*2+1] = ss; }
    __syncthreads();
    if (threadIdx.x == 0){
      float S  = red[0]+red[2]+red[4]+red[6];
      float SS = red[1]+red[3]+red[5]+red[7];
      float mean = S * (1.f/(16*NN));
      float var  = SS * (1.f/(16*NN)) - mean*mean;
      stats[bg*2]   = mean;
      stats[bg*2+1] = rsqrtf(var + 1e-5f);
    }
  } else {
    int i = (bid - 256)*256 + threadIdx.x;
    if (i < 1536*512) wqb[i] = f2bf(wq[i]);
    if (i < 512*512)  wpb[i] = f2bf(wp[i]);
  }
}

// ---- K3: GN apply + transpose -> xnT[b][n][c] bf16 ----
__global__ __launch_bounds__(256) void gn_apply_k(const float* __restrict__ x, const float* __restrict__ stats,
                                                  const float* __restrict__ gw, const float* __restrict__ gb,
                                                  unsigned short* __restrict__ xnT){
  int b = blockIdx.z, c0 = blockIdx.y*64, n0 = blockIdx.x*64;
  __shared__ unsigned short T[64][65];
  int t = threadIdx.x;
  int nl = t & 63;
  int cb = t >> 6;
  #pragma unroll
  for (int r = 0; r < 16; ++r){
    int cl = cb + r*4;
    int c  = c0 + cl;
    float xv   = x[((size_t)b*CH + c)*NN + n0 + nl];
    float mean = stats[(b*GRP + (c>>4))*2];
    float rstd = stats[(b*GRP + (c>>4))*2 + 1];
    float sc   = rstd * gw[c];
    T[cl][nl]  = f2bf((xv - mean)*sc + gb[c]);
  }
  __syncthreads();
  #pragma unroll
  for (int r = 0; r < 16; ++r){
    int nlocal = cb + r*4;
    xnT[((size_t)b*NN + n0 + nlocal)*CH + c0 + nl] = T[nl][nlocal];
  }
}

// ---- K4: QKV GEMM, BK=64, T2 swizzle, 32x32x16 MFMA (half the MFMA issues) ----
// Q rows (o<512) pre-scaled by d^-0.5 * log2(e) so attn uses exp2 directly.
__global__ __launch_bounds__(256) void qkv_gemm_k(const unsigned short* __restrict__ wq,
                                                  const unsigned short* __restrict__ xnT,
                                                  unsigned short* __restrict__ qkb,
                                                  unsigned short* __restrict__ vT){
  int b  = blockIdx.z;
  int m0 = blockIdx.y * 128;
  int n0 = blockIdx.x * 128;
  __shared__ unsigned short As[128][64];   // linear dest; content col-swizzled per row (srow XOR)
  __shared__ unsigned short Bs[128][64];
  int t = threadIdx.x;
  int w = t >> 6, l = t & 63;
  int wm = w >> 1, wn = w & 1;
  f32x16 acc[2][2] = {};                   // [am][bn] 32x32 sub-tiles of the wave's 64x64
  const unsigned short* Ag = wq  + (size_t)(m0 + w*32)*512;
  const unsigned short* Bg = xnT + ((size_t)b*NN + n0 + w*32)*512;
  int srow = l >> 3;                       // row within 8-row chunk
  int c8 = ((l & 7) ^ srow) * 8;           // pre-swizzled source col (shorts)
  int lo5 = l & 31, hi = l >> 5;
  int xr = (lo5 & 7) << 3;                 // read-side XOR (shorts)
  for (int k0 = 0; k0 < 512; k0 += 64){
    #pragma unroll
    for (int i = 0; i < 4; ++i){
      gload_lds16(Ag + (size_t)(i*8 + srow)*512 + k0 + c8, &As[w*32 + i*8][0]);
      gload_lds16(Bg + (size_t)(i*8 + srow)*512 + k0 + c8, &Bs[w*32 + i*8][0]);
    }
    __syncthreads();
    #pragma unroll
    for (int ks = 0; ks < 4; ++ks){
      int cc = (ks*16 + hi*8) ^ xr;
      bf16x8 a0 = *(const bf16x8*)&As[wm*64 +      lo5][cc];
      bf16x8 a1 = *(const bf16x8*)&As[wm*64 + 32 + lo5][cc];
      bf16x8 b0 = *(const bf16x8*)&Bs[wn*64 +      lo5][cc];
      bf16x8 b1 = *(const bf16x8*)&Bs[wn*64 + 32 + lo5][cc];
      acc[0][0] = __builtin_amdgcn_mfma_f32_32x32x16_bf16(a0, b0, acc[0][0], 0, 0, 0);
      acc[0][1] = __builtin_amdgcn_mfma_f32_32x32x16_bf16(a0, b1, acc[0][1], 0, 0, 0);
      acc[1][0] = __builtin_amdgcn_mfma_f32_32x32x16_bf16(a1, b0, acc[1][0], 0, 0, 0);
      acc[1][1] = __builtin_amdgcn_mfma_f32_32x32x16_bf16(a1, b1, acc[1][1], 0, 0, 0);
    }
    __syncthreads();
  }
  float scl = (m0 < 512) ? 0.18033688f : 1.0f;   // Q: d^-0.5 * log2(e)
  if (m0 < 1024){
    #pragma unroll
    for (int am = 0; am < 2; ++am)
      #pragma unroll
      for (int bn = 0; bn < 2; ++bn)
        #pragma unroll
        for (int r = 0; r < 16; ++r){
          int o = m0 + wm*64 + am*32 + (r & 3) + 8*(r >> 2) + 4*hi;   // m74/m101 C/D row map
          int n = n0 + wn*64 + bn*32 + lo5;
          qkb[((size_t)b*NN + n)*1024 + o] = f2bf(acc[am][bn][r] * scl);
        }
  } else {
    #pragma unroll
    for (int am = 0; am < 2; ++am)
      #pragma unroll
      for (int bn = 0; bn < 2; ++bn)
        #pragma unroll
        for (int r = 0; r < 16; ++r){
          int o = m0 + wm*64 + am*32 + (r & 3) + 8*(r >> 2) + 4*hi;
          int n = n0 + wn*64 + bn*32 + lo5;
          vT[((size_t)b*512 + (o - 1024))*NN + n] = f2bf(acc[am][bn][r]);
        }
  }
}

// ---- K5: MFMA flash attention, 32x32 path, split-K wave-groups ----
// 512 threads = 2 groups x 4 waves. Group g owns keys [g*512, g*512+512) (8 tiles),
// own 32KB K/V double-buffer. Streaming softmax => exact additive combine at end.
#define STAGE_KV(TT, BUF)                                                                \
  {                                                                                      \
    int jj = kbase + (TT) * KBLK;                                                        \
    _Pragma("unroll") for (int ch = 0; ch < 2; ++ch){                                    \
      gload_lds16(Kg + (size_t)(jj + wl*16 + ch*8 + srow)*1024 + scol,                   \
                  &KV[g][0][BUF][wl*16 + ch*8][0]);                                      \
      gload_lds16(Vg + (size_t)(wl*16 + ch*8 + srow)*NN + jj + scol,                     \
                  &KV[g][1][BUF][wl*16 + ch*8][0]);                                      \
    }                                                                                    \
  }

__global__ __launch_bounds__(512, 4) void attn_k(const unsigned short* __restrict__ qkb,
                                                 const unsigned short* __restrict__ vT,
                                                 unsigned short* __restrict__ attnT){
  int bh = blockIdx.x;               // XCD = h: all blocks of a head share an XCD
  int b = bh >> 3, h = bh & 7;
  int q0 = blockIdx.y * QBLK;
  int t = threadIdx.x;
  int w = t >> 6, l = t & 63;
  int wl = w & 3, g = w >> 2;
  int lo5 = l & 31, hi = l >> 5;

  __shared__ unsigned short KV[2][2][2][64][64];   // [grp][K|Vt][dbuf][row][col(sw)] = 64 KB

  int srow = l >> 3;                 // staging row within 8-row chunk
  int scol = ((l & 7) ^ srow) * 8;   // pre-swizzled source col (shorts)
  const unsigned short* Kg = qkb + (size_t)b*NN*1024 + 512 + h*DH;
  const unsigned short* Vg = vT  + (size_t)(b*NHEAD + h)*DH*NN;
  int kbase = g * 512;               // key offset for this group

  // Q fragments (B-operand of S^T): col q = lo5, k-rows d = ks*16 + hi*8 + j
  bf16x8 qf[4];
  #pragma unroll
  for (int ks = 0; ks < 4; ++ks)
    qf[ks] = *(const bf16x8*)(qkb + ((size_t)b*NN + q0 + wl*32 + lo5)*1024 + h*DH + ks*16 + hi*8);

  float lsum = 0.f;
  f32x16 accO0 = {}, accO1 = {};     // D[q][d]: row q=(r&3)+8(r>>2)+4hi, col d=c*32+lo5

  STAGE_KV(0, 0)
  __syncthreads();

  int xr = (lo5 & 7) * 8;            // read-side XOR (shorts)

  for (int tt = 0; tt < 8; ++tt){
    int cur = tt & 1;
    if (tt < 7) STAGE_KV(tt + 1, cur ^ 1)

    #pragma unroll
    for (int f = 0; f < 2; ++f){
      // K A-frags: row key = f*32+lo5, k-col d = ks*16+hi*8+j
      bf16x8 kf[4];
      #pragma unroll
      for (int ks = 0; ks < 4; ++ks)
        kf[ks] = *(const bf16x8*)&KV[g][0][cur][f*32 + lo5][(ks*16 + hi*8) ^ xr];

      f32x16 sT = {};
      __builtin_amdgcn_s_setprio(1);
      #pragma unroll
      for (int ks = 0; ks < 4; ++ks)
        sT = __builtin_amdgcn_mfma_f32_32x32x16_bf16(kf[ks], qf[ks], sT, 0, 0, 0);
      __builtin_amdgcn_s_setprio(0);

      // P = exp2(S^T)  (Q pre-scaled by d^-0.5*log2e)
      float p[16];
      #pragma unroll
      for (int r = 0; r < 16; ++r){ p[r] = exp2f(sT[r]); lsum += p[r]; }

      #pragma unroll
      for (int mh = 0; mh < 2; ++mh){      // key 16-step m = f*2 + mh
        int mc = ((f*2 + mh)*16 + hi*8) ^ xr;
        bf16x8 vf0 = *(const bf16x8*)&KV[g][1][cur][lo5][mc];        // d-col block 0
        bf16x8 vf1 = *(const bf16x8*)&KV[g][1][cur][32 + lo5][mc];   // d-col block 1
        int mm = mh*8;
        unsigned x1 = pack2bf(p[mm+0], p[mm+1]);
        unsigned y1 = pack2bf(p[mm+4], p[mm+5]);
        unsigned x2 = pack2bf(p[mm+2], p[mm+3]);
        unsigned y2 = pack2bf(p[mm+6], p[mm+7]);
        plswap(x1, y1);
        plswap(x2, y2);
        union { unsigned u[4]; bf16x8 v; } pf;
        pf.u[0] = x1; pf.u[1] = x2; pf.u[2] = y1; pf.u[3] = y2;
        __builtin_amdgcn_s_setprio(1);
        accO0 = __builtin_amdgcn_mfma_f32_32x32x16_bf16(pf.v, vf0, accO0, 0, 0, 0);
        accO1 = __builtin_amdgcn_mfma_f32_32x32x16_bf16(pf.v, vf1, accO1, 0, 0, 0);
        __builtin_amdgcn_s_setprio(0);
      }
    }
    __syncthreads();
  }

  // ---- cross-group combine (exact: streaming softmax partials are plain sums) ----
  float* Sc = (float*)&KV[0][0][0][0][0];   // 16384 floats of scratch
  if (g == 1){
    int base = wl*2048 + l*4;
    #pragma unroll
    for (int k = 0; k < 4; ++k){
      f32x4 v0 = { accO0[k*4+0], accO0[k*4+1], accO0[k*4+2], accO0[k*4+3] };
      *(f32x4*)&Sc[base + k*256] = v0;
      f32x4 v1 = { accO1[k*4+0], accO1[k*4+1], accO1[k*4+2], accO1[k*4+3] };
      *(f32x4*)&Sc[base + (4+k)*256] = v1;
    }
    Sc[8192 + wl*64 + l] = lsum;
  }
  __syncthreads();
  if (g == 0){
    int base = wl*2048 + l*4;
    #pragma unroll
    for (int k = 0; k < 4; ++k){
      f32x4 v0 = *(const f32x4*)&Sc[base + k*256];
      f32x4 v1 = *(const f32x4*)&Sc[base + (4+k)*256];
      #pragma unroll
      for (int j = 0; j < 4; ++j){
        accO0[k*4+j] += v0[j];
        accO1[k*4+j] += v1[j];
      }
    }
    lsum += Sc[8192 + wl*64 + l];

    // lane covers half the keys for q=lo5; partner (xor 32) has the rest
    lsum += __shfl_xor(lsum, 32);
    float inv = 1.f / lsum;          // lane holds inv for q = lo5

    float invq[16];
    #pragma unroll
    for (int r = 0; r < 16; ++r)
      invq[r] = __shfl(inv, (r & 3) + 8*(r >> 2) + 4*hi);

    #pragma unroll
    for (int r = 0; r < 16; ++r){
      int qr = (r & 3) + 8*(r >> 2) + 4*hi;
      unsigned short* dst = attnT + ((size_t)b*NN + q0 + wl*32 + qr)*CH + h*DH + lo5;
      dst[0]  = f2bf(accO0[r] * invq[r]);
      dst[32] = f2bf(accO1[r] * invq[r]);
    }
  }
}

// ---- K6: proj GEMM 64x128 tiles, BK=64 + swizzle, 32x32x16 MFMA, + residual ----
__global__ __launch_bounds__(256) void proj_gemm_k(const unsigned short* __restrict__ wp,
                                                   const unsigned short* __restrict__ attnT,
                                                   const float* __restrict__ x, float* __restrict__ out){
  int b  = blockIdx.z;
  int m0 = blockIdx.y * 64;
  int n0 = blockIdx.x * 128;
  __shared__ unsigned short As[64][64];
  __shared__ unsigned short Bs[128][64];
  int t = threadIdx.x;
  int w = t >> 6, l = t & 63;
  int wm = w >> 1, wn = w & 1;
  f32x16 acc[2] = {};                      // [bn] 32x64 wave tile = 1x2 of 32x32
  const unsigned short* Ag = wp    + (size_t)(m0 + w*16)*512;
  const unsigned short* Bg = attnT + ((size_t)b*NN + n0 + w*32)*512;
  int srow = l >> 3;
  int c8 = ((l & 7) ^ srow) * 8;
  int lo5 = l & 31, hi = l >> 5;
  int xr = (lo5 & 7) << 3;
  for (int k0 = 0; k0 < 512; k0 += 64){
    #pragma unroll
    for (int i = 0; i < 2; ++i)
      gload_lds16(Ag + (size_t)(i*8 + srow)*512 + k0 + c8, &As[w*16 + i*8][0]);
    #pragma unroll
    for (int i = 0; i < 4; ++i)
      gload_lds16(Bg + (size_t)(i*8 + srow)*512 + k0 + c8, &Bs[w*32 + i*8][0]);
    __syncthreads();
    #pragma unroll
    for (int ks = 0; ks < 4; ++ks){
      int cc = (ks*16 + hi*8) ^ xr;
      bf16x8 a0 = *(const bf16x8*)&As[wm*32 +      lo5][cc];
      bf16x8 b0 = *(const bf16x8*)&Bs[wn*64 +      lo5][cc];
      bf16x8 b1 = *(const bf16x8*)&Bs[wn*64 + 32 + lo5][cc];
      acc[0] = __builtin_amdgcn_mfma_f32_32x32x16_bf16(a0, b0, acc[0], 0, 0, 0);
      acc[1] = __builtin_amdgcn_mfma_f32_32x32x16_bf16(a0, b1, acc[1], 0, 0, 0);
    }
    __syncthreads();
  }
  #pragma unroll
  for (int bn = 0; bn < 2; ++bn)
    #pragma unroll
    for (int r = 0; r < 16; ++r){
      int o = m0 + wm*32 + (r & 3) + 8*(r >> 2) + 4*hi;
      int n = n0 + wn*64 + bn*32 + lo5;
      size_t idx = ((size_t)b*CH + o)*NN + n;
      out[idx] = x[idx] + acc[bn][r];
    }
}

extern "C" void kernel_launch(void* const* d_in, const int* in_sizes, int n_in,
                              void* d_out, int out_size, void* d_ws, size_t ws_size,
                              hipStream_t stream){
  const float* x  = (const float*)d_in[0];
  const float* gw = (const float*)d_in[1];
  const float* gb = (const float*)d_in[2];
  const float* wq = (const float*)d_in[3];
  const float* wp = (const float*)d_in[4];
  float* out = (float*)d_out;
  char* ws = (char*)d_ws;
  float*          stats = (float*)(ws + OFF_STATS);
  unsigned short* wqb   = (unsigned short*)(ws + OFF_WQB);
  unsigned short* wpb   = (unsigned short*)(ws + OFF_WPB);
  unsigned short* xnT   = (unsigned short*)(ws + OFF_XNT);
  unsigned short* qkb   = (unsigned short*)(ws + OFF_QKB);
  unsigned short* vT    = (unsigned short*)(ws + OFF_VT);
  unsigned short* attnT = (unsigned short*)(ws + OFF_ATTNT);

  hipLaunchKernelGGL(pre_k,      dim3(3328),      dim3(256), 0, stream, x, wq, wp, stats, wqb, wpb);
  hipLaunchKernelGGL(gn_apply_k, dim3(16, 8, 8),  dim3(256), 0, stream, x, stats, gw, gb, xnT);
  hipLaunchKernelGGL(qkv_gemm_k, dim3(8, 12, 8),  dim3(256), 0, stream, wqb, xnT, qkb, vT);
  hipLaunchKernelGGL(attn_k,     dim3(64, 8),     dim3(512), 0, stream, qkb, vT, attnT);
  hipLaunchKernelGGL(proj_gemm_k,dim3(8, 8, 8),   dim3(256), 0, stream, wpb, attnT, x, out);
}